// Round 11
// baseline (917.145 us; speedup 1.0000x reference)
//
#include <hip/hip_runtime.h>

#define DIM 64
#define EPS 1e-8f
#define RPB 128            // rows per bucket
#define RPB_SH 7
#define MAXBUC 1024        // LDS bound on bucket count (n <= 131072)
#define NCHUNK 512         // chunk blocks for hist/place (2 blocks/CU)

// ---------------------------------------------------------------------------
// Pipeline (bucket-CSR, all atomics in LDS):
//   hist     : per-chunk LDS histogram over buckets (bucket = row>>7)
//   colscan  : per-bucket exclusive scan across the NCHUNK chunks
//   basescan : exclusive scan of bucket totals -> base[]
//   place    : re-read edges, LDS cursors, write packed (rlow<<17|col);
//              consecutive ranks -> ~32B write runs (round-8 sort wrote 4B
//              random: 106MB HBM for 6.4MB useful, 0.8 TB/s wall)
//   gather   : block per bucket; acc[128][64] in LDS; readlane-broadcast
//              packed entries, coalesced 256B x[col] loads, LDS atomicAdd;
//              z = deg*x + acc  -> d_out   (8-deep MLP: only ~3 waves/SIMD
//              resident at 782 blocks, so per-wave load depth must carry
//              the latency hiding)
//   out      : agg = z@fc_w^T + 2*deg*fc_b ; alpha/beta/gamma; divide
// Algebra: agg[i] = z[i]@W^T + 2*deg_i*b with z = deg*x + sum x[col]
// (degree IS the out-degree, h never materialized).
// ---------------------------------------------------------------------------

__global__ __launch_bounds__(256) void hist_kernel(
    const int* __restrict__ ei, int* __restrict__ hist,
    int E, int nbuc, int chunk)
{
  __shared__ int hl[MAXBUC];
  const int t = threadIdx.x;
  for (int b = t; b < nbuc; b += 256) hl[b] = 0;
  __syncthreads();
  const int e0 = blockIdx.x * chunk;
  const int e1 = min(E, e0 + chunk);
  for (int e = e0 + t; e < e1; e += 256)
    atomicAdd(&hl[ei[e] >> RPB_SH], 1);
  __syncthreads();
  int* hrow = hist + (size_t)blockIdx.x * nbuc;
  for (int b = t; b < nbuc; b += 256) hrow[b] = hl[b];
}

// per-bucket exclusive scan over the NCHUNK chunk-histograms (in place)
__global__ __launch_bounds__(NCHUNK) void colscan_kernel(
    int* __restrict__ hist, int* __restrict__ total, int nbuc)
{
  __shared__ int s[NCHUNK];
  const int t = threadIdx.x;
  const int b = blockIdx.x;
  const int v = hist[(size_t)t * nbuc + b];
  s[t] = v;
  __syncthreads();
  for (int st = 1; st < NCHUNK; st <<= 1) {
    int a = (t >= st) ? s[t - st] : 0;
    __syncthreads();
    s[t] += a;
    __syncthreads();
  }
  hist[(size_t)t * nbuc + b] = s[t] - v;
  if (t == NCHUNK - 1) total[b] = s[t];
}

__global__ __launch_bounds__(1024) void basescan_kernel(
    const int* __restrict__ total, int* __restrict__ base, int nbuc)
{
  __shared__ int s[1024];
  const int t = threadIdx.x;
  const int v = (t < nbuc) ? total[t] : 0;
  s[t] = v;
  __syncthreads();
  for (int st = 1; st < 1024; st <<= 1) {
    int a = (t >= st) ? s[t - st] : 0;
    __syncthreads();
    s[t] += a;
    __syncthreads();
  }
  if (t < nbuc) base[t] = s[t] - v;
  if (t == 1023) base[nbuc] = s[1023];
}

__global__ __launch_bounds__(256) void place_kernel(
    const int* __restrict__ ei, const int* __restrict__ hist,
    const int* __restrict__ base, unsigned int* __restrict__ packed,
    int E, int nbuc, int chunk)
{
  __shared__ int cl[MAXBUC];
  const int t = threadIdx.x;
  const int bk = blockIdx.x;
  for (int b = t; b < nbuc; b += 256)
    cl[b] = base[b] + hist[(size_t)bk * nbuc + b];
  __syncthreads();
  const int e0 = bk * chunk;
  const int e1 = min(E, e0 + chunk);
  for (int e = e0 + t; e < e1; e += 256) {
    const int r = ei[e];
    const int c = ei[E + e];
    const int p = atomicAdd(&cl[r >> RPB_SH], 1);   // LDS atomic, ~20cyc
    packed[p] = ((unsigned int)(r & (RPB - 1)) << 17) | (unsigned int)c;
  }
}

// block per bucket; acc in LDS; 8-deep batched gather with readlane broadcast
__global__ __launch_bounds__(256) void gather_kernel(
    const float* __restrict__ x, const unsigned int* __restrict__ packed,
    const int* __restrict__ base, const float* __restrict__ degree,
    float* __restrict__ z, int n)
{
  __shared__ float acc[RPB * DIM];    // 32 KB
  const int t = threadIdx.x;
  const int lane = t & 63;
  const int w = t >> 6;
  const int b = blockIdx.x;
  for (int i = t; i < RPB * DIM; i += 256) acc[i] = 0.f;
  __syncthreads();

  const int s0 = base[b];
  const int cnt = base[b + 1] - s0;
  const int nch = (cnt + 63) >> 6;    // 64-edge chunks, wave-interleaved
  for (int q = w; q < nch; q += 4) {
    const int c0 = q << 6;
    const int rem = min(64, cnt - c0);
    unsigned int pkv = 0u;
    if (lane < rem) pkv = packed[s0 + c0 + lane];   // coalesced 256B
    int j = 0;
    for (; j + 8 <= rem; j += 8) {    // 8 indep 256B loads in flight
      const unsigned int p0 = __builtin_amdgcn_readlane(pkv, j + 0);
      const unsigned int p1 = __builtin_amdgcn_readlane(pkv, j + 1);
      const unsigned int p2 = __builtin_amdgcn_readlane(pkv, j + 2);
      const unsigned int p3 = __builtin_amdgcn_readlane(pkv, j + 3);
      const unsigned int p4 = __builtin_amdgcn_readlane(pkv, j + 4);
      const unsigned int p5 = __builtin_amdgcn_readlane(pkv, j + 5);
      const unsigned int p6 = __builtin_amdgcn_readlane(pkv, j + 6);
      const unsigned int p7 = __builtin_amdgcn_readlane(pkv, j + 7);
      const float v0 = x[((size_t)(p0 & 0x1FFFFu) << 6) | lane];
      const float v1 = x[((size_t)(p1 & 0x1FFFFu) << 6) | lane];
      const float v2 = x[((size_t)(p2 & 0x1FFFFu) << 6) | lane];
      const float v3 = x[((size_t)(p3 & 0x1FFFFu) << 6) | lane];
      const float v4 = x[((size_t)(p4 & 0x1FFFFu) << 6) | lane];
      const float v5 = x[((size_t)(p5 & 0x1FFFFu) << 6) | lane];
      const float v6 = x[((size_t)(p6 & 0x1FFFFu) << 6) | lane];
      const float v7 = x[((size_t)(p7 & 0x1FFFFu) << 6) | lane];
      atomicAdd(&acc[((p0 >> 17) << 6) | lane], v0);  // ds_add_f32, 2-way max
      atomicAdd(&acc[((p1 >> 17) << 6) | lane], v1);
      atomicAdd(&acc[((p2 >> 17) << 6) | lane], v2);
      atomicAdd(&acc[((p3 >> 17) << 6) | lane], v3);
      atomicAdd(&acc[((p4 >> 17) << 6) | lane], v4);
      atomicAdd(&acc[((p5 >> 17) << 6) | lane], v5);
      atomicAdd(&acc[((p6 >> 17) << 6) | lane], v6);
      atomicAdd(&acc[((p7 >> 17) << 6) | lane], v7);
    }
    for (; j < rem; ++j) {
      const unsigned int p0 = __builtin_amdgcn_readlane(pkv, j);
      const float v0 = x[((size_t)(p0 & 0x1FFFFu) << 6) | lane];
      atomicAdd(&acc[((p0 >> 17) << 6) | lane], v0);
    }
  }
  __syncthreads();

  const int node0 = b << RPB_SH;
  for (int i = t; i < RPB * DIM; i += 256) {
    const int node = node0 + (i >> 6);
    if (node < n) {
      const int d = i & 63;
      z[((size_t)node << 6) | d] =
          degree[node] * x[((size_t)node << 6) | d] + acc[i];
    }
  }
}

// Fused epilogue (round-7 readlane design, unchanged): wave m owns matrix m,
// row `lane` in 64 VGPRs; per node one coalesced 256B src load; k-broadcast
// via v_readlane; results staged in LDS; combine does relu/div + store.
__global__ __launch_bounds__(256) void out_kernel(
    const float* __restrict__ x,
    const float* __restrict__ fc_w,  const float* __restrict__ fc_b,
    const float* __restrict__ dir_w, const float* __restrict__ dir_b,
    const float* __restrict__ neu_w, const float* __restrict__ neu_b,
    const float* __restrict__ rob_w, const float* __restrict__ rob_b,
    const float* __restrict__ degree, float* __restrict__ out, int n)
{
  __shared__ float res_lds[4][16][DIM];   // 16 KB
  __shared__ float fcb_lds[DIM];
  const int t = threadIdx.x;
  const int m = t >> 6;
  const int lane = t & 63;

  const float* wm = (m == 0) ? fc_w : (m == 1) ? dir_w
                  : (m == 2) ? neu_w : rob_w;
  const float* bm = (m == 0) ? fc_b : (m == 1) ? dir_b
                  : (m == 2) ? neu_b : rob_b;
  if (t < DIM) fcb_lds[t] = fc_b[t];

  float wreg[64];
  const float* wrow = wm + lane * DIM;
#pragma unroll
  for (int k4 = 0; k4 < 16; ++k4) {
    const float4 w = *(const float4*)&wrow[k4 << 2];
    wreg[(k4 << 2) + 0] = w.x; wreg[(k4 << 2) + 1] = w.y;
    wreg[(k4 << 2) + 2] = w.z; wreg[(k4 << 2) + 3] = w.w;
  }
  const float bias = bm[lane];
  const float* srcbase = (m == 0) ? out : x;   // z lives in d_out
  __syncthreads();

  const int ntiles = (n + 15) >> 4;
  for (int tile = blockIdx.x; tile < ntiles; tile += gridDim.x) {
    const int node0 = tile << 4;
    const int cnt = (n - node0 < 16) ? (n - node0) : 16;

    float v = srcbase[((size_t)node0 << 6) | lane];
    for (int i = 0; i < cnt; ++i) {
      float vn = 0.f;
      if (i + 1 < cnt) vn = srcbase[((size_t)(node0 + i + 1) << 6) | lane];
      const int vi = __float_as_int(v);
      float a0 = 0.f, a1 = 0.f, a2 = 0.f, a3 = 0.f;
#pragma unroll
      for (int k = 0; k < 64; k += 4) {
        a0 = fmaf(wreg[k + 0],
                  __int_as_float(__builtin_amdgcn_readlane(vi, k + 0)), a0);
        a1 = fmaf(wreg[k + 1],
                  __int_as_float(__builtin_amdgcn_readlane(vi, k + 1)), a1);
        a2 = fmaf(wreg[k + 2],
                  __int_as_float(__builtin_amdgcn_readlane(vi, k + 2)), a2);
        a3 = fmaf(wreg[k + 3],
                  __int_as_float(__builtin_amdgcn_readlane(vi, k + 3)), a3);
      }
      float r = (a0 + a1) + (a2 + a3);
      if (m != 0) r += bias;
      res_lds[m][i][lane] = r;
      v = vn;
    }
    __syncthreads();

#pragma unroll
    for (int e = 0; e < 4; ++e) {
      const int idx = (e << 8) + t;
      const int i = idx >> 6;
      const int d = idx & 63;
      const int node = node0 + i;
      if (i < cnt) {
        const float deg = degree[node];
        const float agg = res_lds[0][i][d] + 2.f * deg * fcb_lds[d];
        const float al = fmaxf(res_lds[1][i][d], 0.f);
        const float be = fmaxf(res_lds[2][i][d], 0.f);
        const float ga = res_lds[3][i][d];
        out[((size_t)node << 6) | d] =
            fmaf(be, agg, ga) / (fmaf(be, deg, al) + EPS);
      }
    }
    __syncthreads();
  }
}

extern "C" void kernel_launch(void* const* d_in, const int* in_sizes, int n_in,
                              void* d_out, int out_size, void* d_ws, size_t ws_size,
                              hipStream_t stream) {
  const float* x      = (const float*)d_in[0];
  const int*   ei     = (const int*)  d_in[1];
  const float* degree = (const float*)d_in[2];
  const float* fc_w   = (const float*)d_in[3];
  const float* fc_b   = (const float*)d_in[4];
  const float* dir_w  = (const float*)d_in[5];
  const float* dir_b  = (const float*)d_in[6];
  const float* neu_w  = (const float*)d_in[7];
  const float* neu_b  = (const float*)d_in[8];
  const float* rob_w  = (const float*)d_in[9];
  const float* rob_b  = (const float*)d_in[10];
  float* out = (float*)d_out;

  const int n = in_sizes[0] / DIM;
  const int E = in_sizes[1] / 2;
  const int nbuc = (n + RPB - 1) >> RPB_SH;        // 782 @ n=100k
  const int chunk = (E + NCHUNK - 1) / NCHUNK;

  // ws: packed(E) | hist(NCHUNK*nbuc) | total(nbuc) | base(nbuc+1)  (~8MB)
  unsigned int* packed = (unsigned int*)d_ws;
  int* hist  = (int*)(packed + E);
  int* total = hist + (size_t)NCHUNK * nbuc;
  int* base  = total + nbuc;

  hipLaunchKernelGGL(hist_kernel, dim3(NCHUNK), dim3(256), 0, stream,
                     ei, hist, E, nbuc, chunk);
  hipLaunchKernelGGL(colscan_kernel, dim3(nbuc), dim3(NCHUNK), 0, stream,
                     hist, total, nbuc);
  hipLaunchKernelGGL(basescan_kernel, dim3(1), dim3(1024), 0, stream,
                     total, base, nbuc);
  hipLaunchKernelGGL(place_kernel, dim3(NCHUNK), dim3(256), 0, stream,
                     ei, hist, base, packed, E, nbuc, chunk);
  hipLaunchKernelGGL(gather_kernel, dim3(nbuc), dim3(256), 0, stream,
                     x, packed, base, degree, out, n);
  hipLaunchKernelGGL(out_kernel, dim3(1536), dim3(256), 0, stream,
                     x, fc_w, fc_b, dir_w, dir_b, neu_w, neu_b, rob_w, rob_b,
                     degree, out, n);
}

// Round 12
// 297.891 us; speedup vs baseline: 3.0788x; 3.0788x over previous
//
#include <hip/hip_runtime.h>

#define DIM 64
#define EPS 1e-8f
#define BUC 512            // rows per bucket (coarse, for sort only)
#define BUC_SH 9
#define MAXBUC 256         // bucket count bound (n <= 131072)
#define NCHUNK 256         // chunk blocks for hist/place
#define CSR_CAP 12288      // LDS staging capacity in csr_build (48 KB)

// ---------------------------------------------------------------------------
// Pipeline = round-8 architecture (400us measured) with ONLY the sort swapped:
//   scan1/2/3 : exclusive scan of degree -> off[]  (row-exact CSR offsets)
//   hist      : per-chunk LDS histogram over 196 buckets (bucket = row>>9)
//   colscan   : per-bucket exclusive scan across the 256 chunks
//   place     : LDS cursors -> packed (rlow<<17|col) grouped by bucket;
//               ~128B write runs (round-8 global-atomic sort: 4B random
//               scatter = 106MB HBM writes for 6.4MB useful, 145us @0.8TB/s)
//   csr_build : block per bucket; row cursors seeded from off[]; permute
//               through 48KB LDS buffer; coalesced csr[] writes
//   gather    : UNCHANGED round-8 float4 CSR gather (proven <145us; round-11
//               bucket/LDS-atomic gather regressed to 688us at 2% VALUBusy —
//               scalar 4B lanes + serial schedule killed MLP)
//   out       : UNCHANGED round-7 readlane epilogue (~65us)
// Algebra: agg[i] = z[i]@W^T + 2*deg_i*b with z = deg*x + sum x[col]
// (degree IS the out-degree; h never materialized).
// ---------------------------------------------------------------------------

__global__ __launch_bounds__(256) void scan1_kernel(
    const float* __restrict__ degree, int* __restrict__ off,
    int* __restrict__ bsum, int n)
{
  __shared__ int s[256];
  const int t = threadIdx.x;
  const int i = blockIdx.x * 256 + t;
  const int v = (i < n) ? (int)(degree[i] + 0.5f) : 0;
  s[t] = v;
  __syncthreads();
  for (int st = 1; st < 256; st <<= 1) {
    int a = (t >= st) ? s[t - st] : 0;
    __syncthreads();
    s[t] += a;
    __syncthreads();
  }
  if (i < n) off[i] = s[t] - v;
  if (t == 255) bsum[blockIdx.x] = s[t];
}

__global__ __launch_bounds__(512) void scan2_kernel(
    const int* __restrict__ bsum, int* __restrict__ bpre,
    int* __restrict__ off, int nb, int ch, int n)
{
  __shared__ int s[512];
  const int t = threadIdx.x;
  const int base = t * ch;
  int local = 0;
  for (int q = 0; q < ch; ++q) {
    const int j = base + q;
    if (j < nb) local += bsum[j];
  }
  s[t] = local;
  __syncthreads();
  for (int st = 1; st < 512; st <<= 1) {
    int a = (t >= st) ? s[t - st] : 0;
    __syncthreads();
    s[t] += a;
    __syncthreads();
  }
  int run = s[t] - local;
  for (int q = 0; q < ch; ++q) {
    const int j = base + q;
    if (j < nb) { bpre[j] = run; run += bsum[j]; }
  }
  if (t == 511) off[n] = s[511];
}

__global__ __launch_bounds__(256) void scan3_kernel(
    int* __restrict__ off, const int* __restrict__ bpre, int n)
{
  const int i = blockIdx.x * 256 + threadIdx.x;
  if (i < n) off[i] += bpre[blockIdx.x];
}

__global__ __launch_bounds__(256) void hist_kernel(
    const int* __restrict__ ei, int* __restrict__ hist,
    int E, int nbuc, int chunk)
{
  __shared__ int hl[MAXBUC];
  const int t = threadIdx.x;
  for (int b = t; b < nbuc; b += 256) hl[b] = 0;
  __syncthreads();
  const int e0 = blockIdx.x * chunk;
  const int e1 = min(E, e0 + chunk);
  for (int e = e0 + t; e < e1; e += 256)
    atomicAdd(&hl[ei[e] >> BUC_SH], 1);
  __syncthreads();
  int* hrow = hist + (size_t)blockIdx.x * nbuc;
  for (int b = t; b < nbuc; b += 256) hrow[b] = hl[b];
}

// per-bucket exclusive scan over the NCHUNK chunk-histograms (in place)
__global__ __launch_bounds__(NCHUNK) void colscan_kernel(
    int* __restrict__ hist, int nbuc)
{
  __shared__ int s[NCHUNK];
  const int t = threadIdx.x;
  const int b = blockIdx.x;
  const int v = hist[(size_t)t * nbuc + b];
  s[t] = v;
  __syncthreads();
  for (int st = 1; st < NCHUNK; st <<= 1) {
    int a = (t >= st) ? s[t - st] : 0;
    __syncthreads();
    s[t] += a;
    __syncthreads();
  }
  hist[(size_t)t * nbuc + b] = s[t] - v;
}

__global__ __launch_bounds__(256) void place_kernel(
    const int* __restrict__ ei, const int* __restrict__ hist,
    const int* __restrict__ off, unsigned int* __restrict__ packed,
    int E, int n, int nbuc, int chunk)
{
  __shared__ int cl[MAXBUC];
  const int t = threadIdx.x;
  const int bk = blockIdx.x;
  for (int b = t; b < nbuc; b += 256)
    cl[b] = off[b << BUC_SH] + hist[(size_t)bk * nbuc + b];  // base + prefix
  __syncthreads();
  const int e0 = bk * chunk;
  const int e1 = min(E, e0 + chunk);
  for (int e = e0 + t; e < e1; e += 256) {
    const int r = ei[e];
    const int c = ei[E + e];
    const int p = atomicAdd(&cl[r >> BUC_SH], 1);        // LDS atomic
    packed[p] = ((unsigned int)(r & (BUC - 1)) << 17) | (unsigned int)c;
  }
}

// block per bucket: row cursors from off[]; permute via LDS; coalesced write
__global__ __launch_bounds__(512) void csrbuild_kernel(
    const unsigned int* __restrict__ packed, const int* __restrict__ off,
    int* __restrict__ csr, int n)
{
  __shared__ int cur[BUC];
  __shared__ int colbuf[CSR_CAP];
  const int b = blockIdx.x;
  const int t = threadIdx.x;
  const int node0 = b << BUC_SH;
  const int nrows = min(BUC, n - node0);
  const int base = off[node0];
  const int end  = off[min(node0 + BUC, n)];
  const int cnt = end - base;
  if (t < nrows) cur[t] = off[node0 + t] - base;
  __syncthreads();
  if (cnt <= CSR_CAP) {
    for (int i = t; i < cnt; i += 512) {
      const unsigned int p = packed[base + i];          // coalesced read
      const int pos = atomicAdd(&cur[p >> 17], 1);      // LDS cursor
      colbuf[pos] = (int)(p & 0x1FFFFu);
    }
    __syncthreads();
    for (int i = t; i < cnt; i += 512)
      csr[base + i] = colbuf[i];                        // coalesced write
  } else {   // oversized bucket (pathological skew): direct-global fallback
    for (int i = t; i < cnt; i += 512) {
      const unsigned int p = packed[base + i];
      const int pos = atomicAdd(&cur[p >> 17], 1);
      csr[base + pos] = (int)(p & 0x1FFFFu);
    }
  }
}

// UNCHANGED round-8 gather: z[i] = deg_i*x[i] + sum_j x[csr[j]]
// float4 lanes, 4 edges per wave-step, zero LDS, 8 waves/SIMD.
__global__ __launch_bounds__(256, 8) void gather_kernel(
    const float* __restrict__ x, const int* __restrict__ off,
    const int* __restrict__ csr, const float* __restrict__ degree,
    float* __restrict__ z, int n)
{
  const int lane = threadIdx.x & 63;
  const int sub = lane >> 4;
  const int l16 = lane & 15;
  const int wid = (blockIdx.x << 2) + (threadIdx.x >> 6);
  const int nwaves = gridDim.x << 2;
  for (int node = wid; node < n; node += nwaves) {
    float4 acc = make_float4(0.f, 0.f, 0.f, 0.f);
    if (sub == 0) {
      const float4 xv = *(const float4*)&x[((size_t)node << 6) + (l16 << 2)];
      const float d = degree[node];
      acc.x = d * xv.x; acc.y = d * xv.y; acc.z = d * xv.z; acc.w = d * xv.w;
    }
    const int o0 = off[node];
    const int o1 = off[node + 1];
    int j = o0;
    for (; j + 8 <= o1; j += 8) {
      const int c0 = csr[j + sub];
      const int c1 = csr[j + 4 + sub];
      const float4 v0 = *(const float4*)&x[((size_t)c0 << 6) + (l16 << 2)];
      const float4 v1 = *(const float4*)&x[((size_t)c1 << 6) + (l16 << 2)];
      acc.x += v0.x + v1.x; acc.y += v0.y + v1.y;
      acc.z += v0.z + v1.z; acc.w += v0.w + v1.w;
    }
    if (j + 4 <= o1) {
      const int c = csr[j + sub];
      const float4 v = *(const float4*)&x[((size_t)c << 6) + (l16 << 2)];
      acc.x += v.x; acc.y += v.y; acc.z += v.z; acc.w += v.w;
      j += 4;
    }
    const int rem = o1 - j;
    if (sub < rem) {
      const int c = csr[j + sub];
      const float4 v = *(const float4*)&x[((size_t)c << 6) + (l16 << 2)];
      acc.x += v.x; acc.y += v.y; acc.z += v.z; acc.w += v.w;
    }
    acc.x += __shfl_xor(acc.x, 16, 64); acc.y += __shfl_xor(acc.y, 16, 64);
    acc.z += __shfl_xor(acc.z, 16, 64); acc.w += __shfl_xor(acc.w, 16, 64);
    acc.x += __shfl_xor(acc.x, 32, 64); acc.y += __shfl_xor(acc.y, 32, 64);
    acc.z += __shfl_xor(acc.z, 32, 64); acc.w += __shfl_xor(acc.w, 32, 64);
    if (sub == 0) {
      *(float4*)&z[((size_t)node << 6) + (l16 << 2)] = acc;
    }
  }
}

// UNCHANGED round-7 readlane epilogue.
__global__ __launch_bounds__(256) void out_kernel(
    const float* __restrict__ x,
    const float* __restrict__ fc_w,  const float* __restrict__ fc_b,
    const float* __restrict__ dir_w, const float* __restrict__ dir_b,
    const float* __restrict__ neu_w, const float* __restrict__ neu_b,
    const float* __restrict__ rob_w, const float* __restrict__ rob_b,
    const float* __restrict__ degree, float* __restrict__ out, int n)
{
  __shared__ float res_lds[4][16][DIM];   // 16 KB
  __shared__ float fcb_lds[DIM];
  const int t = threadIdx.x;
  const int m = t >> 6;
  const int lane = t & 63;

  const float* wm = (m == 0) ? fc_w : (m == 1) ? dir_w
                  : (m == 2) ? neu_w : rob_w;
  const float* bm = (m == 0) ? fc_b : (m == 1) ? dir_b
                  : (m == 2) ? neu_b : rob_b;
  if (t < DIM) fcb_lds[t] = fc_b[t];

  float wreg[64];
  const float* wrow = wm + lane * DIM;
#pragma unroll
  for (int k4 = 0; k4 < 16; ++k4) {
    const float4 w = *(const float4*)&wrow[k4 << 2];
    wreg[(k4 << 2) + 0] = w.x; wreg[(k4 << 2) + 1] = w.y;
    wreg[(k4 << 2) + 2] = w.z; wreg[(k4 << 2) + 3] = w.w;
  }
  const float bias = bm[lane];
  const float* srcbase = (m == 0) ? out : x;   // z lives in d_out
  __syncthreads();

  const int ntiles = (n + 15) >> 4;
  for (int tile = blockIdx.x; tile < ntiles; tile += gridDim.x) {
    const int node0 = tile << 4;
    const int cnt = (n - node0 < 16) ? (n - node0) : 16;

    float v = srcbase[((size_t)node0 << 6) | lane];
    for (int i = 0; i < cnt; ++i) {
      float vn = 0.f;
      if (i + 1 < cnt) vn = srcbase[((size_t)(node0 + i + 1) << 6) | lane];
      const int vi = __float_as_int(v);
      float a0 = 0.f, a1 = 0.f, a2 = 0.f, a3 = 0.f;
#pragma unroll
      for (int k = 0; k < 64; k += 4) {
        a0 = fmaf(wreg[k + 0],
                  __int_as_float(__builtin_amdgcn_readlane(vi, k + 0)), a0);
        a1 = fmaf(wreg[k + 1],
                  __int_as_float(__builtin_amdgcn_readlane(vi, k + 1)), a1);
        a2 = fmaf(wreg[k + 2],
                  __int_as_float(__builtin_amdgcn_readlane(vi, k + 2)), a2);
        a3 = fmaf(wreg[k + 3],
                  __int_as_float(__builtin_amdgcn_readlane(vi, k + 3)), a3);
      }
      float r = (a0 + a1) + (a2 + a3);
      if (m != 0) r += bias;
      res_lds[m][i][lane] = r;
      v = vn;
    }
    __syncthreads();

#pragma unroll
    for (int e = 0; e < 4; ++e) {
      const int idx = (e << 8) + t;
      const int i = idx >> 6;
      const int d = idx & 63;
      const int node = node0 + i;
      if (i < cnt) {
        const float deg = degree[node];
        const float agg = res_lds[0][i][d] + 2.f * deg * fcb_lds[d];
        const float al = fmaxf(res_lds[1][i][d], 0.f);
        const float be = fmaxf(res_lds[2][i][d], 0.f);
        const float ga = res_lds[3][i][d];
        out[((size_t)node << 6) | d] =
            fmaf(be, agg, ga) / (fmaf(be, deg, al) + EPS);
      }
    }
    __syncthreads();
  }
}

extern "C" void kernel_launch(void* const* d_in, const int* in_sizes, int n_in,
                              void* d_out, int out_size, void* d_ws, size_t ws_size,
                              hipStream_t stream) {
  const float* x      = (const float*)d_in[0];
  const int*   ei     = (const int*)  d_in[1];
  const float* degree = (const float*)d_in[2];
  const float* fc_w   = (const float*)d_in[3];
  const float* fc_b   = (const float*)d_in[4];
  const float* dir_w  = (const float*)d_in[5];
  const float* dir_b  = (const float*)d_in[6];
  const float* neu_w  = (const float*)d_in[7];
  const float* neu_b  = (const float*)d_in[8];
  const float* rob_w  = (const float*)d_in[9];
  const float* rob_b  = (const float*)d_in[10];
  float* out = (float*)d_out;

  const int n = in_sizes[0] / DIM;
  const int E = in_sizes[1] / 2;
  const int NB = (n + 255) / 256;
  const int CH = (NB + 511) / 512;
  const int nbuc = (n + BUC - 1) >> BUC_SH;        // 196 @ n=100k
  const int nchunkE = (E + NCHUNK - 1) / NCHUNK;

  // ws: off(n+1) | bsum(NB) | bpre(NB) | packed(E) | hist(NCHUNK*nbuc) | csr(E)
  int* off  = (int*)d_ws;
  int* bsum = off + (n + 1);
  int* bpre = bsum + NB;
  unsigned int* packed = (unsigned int*)(bpre + NB);
  int* hist = (int*)(packed + E);
  int* csr  = hist + (size_t)NCHUNK * nbuc;

  hipLaunchKernelGGL(scan1_kernel, dim3(NB), dim3(256), 0, stream,
                     degree, off, bsum, n);
  hipLaunchKernelGGL(scan2_kernel, dim3(1), dim3(512), 0, stream,
                     bsum, bpre, off, NB, CH, n);
  hipLaunchKernelGGL(scan3_kernel, dim3(NB), dim3(256), 0, stream,
                     off, bpre, n);
  hipLaunchKernelGGL(hist_kernel, dim3(NCHUNK), dim3(256), 0, stream,
                     ei, hist, E, nbuc, nchunkE);
  hipLaunchKernelGGL(colscan_kernel, dim3(nbuc), dim3(NCHUNK), 0, stream,
                     hist, nbuc);
  hipLaunchKernelGGL(place_kernel, dim3(NCHUNK), dim3(256), 0, stream,
                     ei, hist, off, packed, E, n, nbuc, nchunkE);
  hipLaunchKernelGGL(csrbuild_kernel, dim3(nbuc), dim3(512), 0, stream,
                     packed, off, csr, n);
  hipLaunchKernelGGL(gather_kernel, dim3(2048), dim3(256), 0, stream,
                     x, off, csr, degree, out, n);
  hipLaunchKernelGGL(out_kernel, dim3(1536), dim3(256), 0, stream,
                     x, fc_w, fc_b, dir_w, dir_b, neu_w, neu_b, rob_w, rob_b,
                     degree, out, n);
}